// Round 14
// baseline (36.883 us; speedup 1.0000x reference)
//
#include <hip/hip_runtime.h>
#include <hip/hip_bf16.h>

#define B_   128
#define N_   128
#define FA   64
#define FB   16
#define K1   144   // 2*FA + FB
#define KP   160   // K padded to 5 * 32
#define HID  512
#define OUT_ 128

typedef __attribute__((ext_vector_type(8))) short short8;
typedef __attribute__((ext_vector_type(4))) float f32x4;

__device__ __forceinline__ ushort f2b(float v) {
  __hip_bfloat16 h = __float2bfloat16(v);
  return *reinterpret_cast<ushort*>(&h);
}
__device__ __forceinline__ float4 add4(float4 a, float4 b) {
  return make_float4(a.x + b.x, a.y + b.y, a.z + b.z, a.w + b.w);
}

// ---------------------------------------------------------------------------
// Prep kernel: blocks 0..39 convert W1 -> bf16 fragment order (w1f unit
// U=(ntg*5+ks)*64+g*16+c holds W1[ks*32+g*8+e][ntg*16+c]); block 40 zeroes
// out[] (required: fused kernel atomically accumulates into it).
// ---------------------------------------------------------------------------
__global__ __launch_bounds__(256) void k_prep(
    const float* __restrict__ W1, ushort* __restrict__ w1f,
    float* __restrict__ out) {
  const int t = threadIdx.x;
  if (blockIdx.x == 40) {
    float4* o4 = reinterpret_cast<float4*>(out);
    for (int u = t; u < B_ * OUT_ / 4; u += 256)
      o4[u] = make_float4(0.f, 0.f, 0.f, 0.f);
    return;
  }
  const int U  = blockIdx.x * 256 + t;
  const int c  = U & 15;
  const int g  = (U >> 4) & 3;
  const int t5 = U >> 6;
  const int ks = t5 % 5;
  const int ntg = t5 / 5;
  const int n  = ntg * 16 + c;
  const int k0 = ks * 32 + g * 8;
  short8 v;
#pragma unroll
  for (int e = 0; e < 8; ++e) {
    const int k = k0 + e;
    v[e] = (short)f2b((k < K1) ? W1[k * HID + n] : 0.f);
  }
  reinterpret_cast<short8*>(w1f)[U] = v;
}

// ---------------------------------------------------------------------------
// Fused kernel: one block per (b, 16-row j-tile m). 256 thr = 4 waves.
// Phase 1: proven r7 gather (ballot-compacted sorted i-lists, 4-way is-split
// float4 gather, bf16 row build in LDS).
// Phase 2: fragment-order tile -> 40 MFMA vs L2-hot w1f -> bias+relu+colsum
// of this block's 16 rows -> sS[512] -> FULL 128-o W2 GEMV of the partial
// sS -> atomicAdd all o (8 commutative contributions per out element).
// ---------------------------------------------------------------------------
__global__ __launch_bounds__(256) void k_fused(
    const float* __restrict__ atom, const float* __restrict__ bond,
    const float* __restrict__ adj, const ushort* __restrict__ w1f,
    const float* __restrict__ b1, const float* __restrict__ W2,
    const float* __restrict__ b2, float* __restrict__ out) {
  const int t = threadIdx.x;
  const int bid = blockIdx.x;
  const int b  = bid >> 3;
  const int m  = bid & 7;
  const int j0 = m * 16;
  const int jl = t >> 4;   // 0..15 local row (phase 1)

  __shared__ float  sAdj[N_][16];    // 8 KB
  __shared__ ushort sList[16][N_];   // 4 KB compact active-i lists (sorted)
  __shared__ int    sCnt[16];
  __shared__ float4 sPart[16][4][4]; // 4 KB is-partials
  __shared__ ushort sRow[16][KP];    // 5 KB bf16 rows
  __shared__ uint4  sFrag[320];      // 5 KB fragment-ordered A tile
  __shared__ float  sS[HID];         // 2 KB column sums (this block's rows)
  __shared__ float  sRed[2][OUT_];   // 1 KB W2 partials

  // ---- phase 1: sparse aggregation (verbatim r7 structure) ----
  const float* adjb = adj + (size_t)b * N_ * N_ + j0;
  for (int u = t; u < N_ * 4; u += 256) {
    const int i = u >> 2, q = u & 3;
    *reinterpret_cast<float4*>(&sAdj[i][q * 4]) =
        *reinterpret_cast<const float4*>(&adjb[(size_t)i * N_ + q * 4]);
  }
  __syncthreads();

  const int wv = t >> 6, l = t & 63;
#pragma unroll
  for (int q = 0; q < 4; ++q) {
    const int jj = wv * 4 + q;
    const float a0 = sAdj[l][jj];
    const float a1 = sAdj[l + 64][jj];
    const unsigned long long m0 = __ballot(a0 != 0.f);
    const unsigned long long m1 = __ballot(a1 != 0.f);
    const int c0 = __popcll(m0);
    unsigned int p0 = __builtin_amdgcn_mbcnt_lo((unsigned)m0, 0u);
    p0 = __builtin_amdgcn_mbcnt_hi((unsigned)(m0 >> 32), p0);
    if (a0 != 0.f) sList[jj][p0] = (ushort)l;
    unsigned int p1 = __builtin_amdgcn_mbcnt_lo((unsigned)m1, 0u);
    p1 = __builtin_amdgcn_mbcnt_hi((unsigned)(m1 >> 32), p1);
    if (a1 != 0.f) sList[jj][c0 + p1] = (ushort)(l + 64);
    if (l == 0) sCnt[jj] = c0 + __popcll(m1);
  }
  __syncthreads();

  {
    const int fq = (t >> 2) & 3;
    const int is = t & 3;
    const int cnt = sCnt[jl];
    const float4* bp4 = reinterpret_cast<const float4*>(
        bond + ((size_t)b * N_ * N_ + (j0 + jl)) * FB) + fq;
    float4 a0 = {0,0,0,0}, a1 = {0,0,0,0}, a2 = {0,0,0,0}, a3 = {0,0,0,0};
    int e = is;
    for (; e + 12 < cnt; e += 16) {
      const int i0 = sList[jl][e];
      const int i1 = sList[jl][e + 4];
      const int i2 = sList[jl][e + 8];
      const int i3 = sList[jl][e + 12];
      a0 = add4(a0, bp4[(size_t)i0 * 512]);
      a1 = add4(a1, bp4[(size_t)i1 * 512]);
      a2 = add4(a2, bp4[(size_t)i2 * 512]);
      a3 = add4(a3, bp4[(size_t)i3 * 512]);
    }
    for (; e < cnt; e += 4) a0 = add4(a0, bp4[(size_t)sList[jl][e] * 512]);
    sPart[jl][fq][is] = add4(add4(a0, a1), add4(a2, a3));
  }
  __syncthreads();

  {
    const int f = t & 15;
    const float* pc = reinterpret_cast<const float*>(&sPart[jl][f >> 2][0]);
    const float aggv = ((pc[f & 3] + pc[4 + (f & 3)]) +
                        (pc[8 + (f & 3)] + pc[12 + (f & 3)]));
    const float deg = (float)sCnt[jl];
    const float* ab = atom + ((size_t)b * N_ + j0 + jl) * FA;
    for (int c = f; c < FA; c += 16) {
      const float av = ab[c];
      sRow[jl][c]      = f2b(av);
      sRow[jl][FA + c] = f2b(av * deg);
    }
    sRow[jl][2 * FA + f] = f2b(aggv);
    sRow[jl][K1 + f]     = 0;
  }
  __syncthreads();

  // ---- phase 2a: fragment-order A tile into LDS ----
  for (int u = t; u < 320; u += 256) {
    const int s = u >> 4, j2 = u & 15;        // s = ks*4 + g
    const int ks = s >> 2, g = s & 3;
    sFrag[ks * 64 + g * 16 + j2] =
        *reinterpret_cast<const uint4*>(&sRow[j2][s * 8]);
  }
  __syncthreads();

  // ---- phase 2b: MFMA GEMM (16 rows x 512 cols) + bias/relu/colsum ----
  {
    const short8* a8 = reinterpret_cast<const short8*>(sFrag);
    const short8* w8 = reinterpret_cast<const short8*>(w1f);
    short8 af[5];
#pragma unroll
    for (int ks = 0; ks < 5; ++ks) af[ks] = a8[ks * 64 + l];

    for (int g = 0; g < 8; ++g) {
      const int ntg = wv * 8 + g;           // cols ntg*16 .. +15
      f32x4 acc = {0.f, 0.f, 0.f, 0.f};
#pragma unroll
      for (int ks = 0; ks < 5; ++ks)
        acc = __builtin_amdgcn_mfma_f32_16x16x32_bf16(
            af[ks], w8[(ntg * 5 + ks) * 64 + l], acc, 0, 0, 0);
      const float bias = b1[ntg * 16 + (l & 15)];
      float p = 0.f;
#pragma unroll
      for (int r = 0; r < 4; ++r) p += fmaxf(acc[r] + bias, 0.f);
      p += __shfl_xor(p, 16);
      p += __shfl_xor(p, 32);
      if ((l >> 4) == 0) sS[ntg * 16 + (l & 15)] = p;
    }
  }
  __syncthreads();

  // ---- phase 2c: FULL-o W2 GEMV of this block's partial sS + atomics ----
  {
    const int o  = t & 127;
    const int kh = t >> 7;                   // 0..1, 256 k each
    const float* W2p = W2 + (size_t)(kh * 256) * OUT_ + o;
    const float* sp = sS + kh * 256;
    float acc = 0.f;
#pragma unroll 8
    for (int k = 0; k < 256; ++k) acc += sp[k] * W2p[(size_t)k * OUT_];
    sRed[kh][o] = acc;
  }
  __syncthreads();
  if (t < OUT_) {
    float v = sRed[0][t] + sRed[1][t];
    if (m == 0) v += (float)N_ * b2[t];
    atomicAdd(&out[b * OUT_ + t], v);
  }
}

// ---------------------------------------------------------------------------
extern "C" void kernel_launch(void* const* d_in, const int* in_sizes, int n_in,
                              void* d_out, int out_size, void* d_ws, size_t ws_size,
                              hipStream_t stream) {
  const float* atom = (const float*)d_in[0];
  const float* bond = (const float*)d_in[1];
  const float* adj  = (const float*)d_in[2];
  const float* W1   = (const float*)d_in[3];
  const float* b1   = (const float*)d_in[4];
  const float* W2   = (const float*)d_in[5];
  const float* b2   = (const float*)d_in[6];
  float* out = (float*)d_out;

  ushort* w1f = (ushort*)d_ws;   // 10240 units * 16 B = 160 KB

  k_prep<<<41, 256, 0, stream>>>(W1, w1f, out);
  k_fused<<<B_ * 8, 256, 0, stream>>>(atom, bond, adj, w1f, b1, W2, b2, out);
}

// Round 15
// 25.672 us; speedup vs baseline: 1.4367x; 1.4367x over previous
//
#include <hip/hip_runtime.h>
#include <hip/hip_bf16.h>

#define B_   128
#define N_   128
#define FA   64
#define FB   16
#define K1   144   // 2*FA + FB
#define KP   160   // K padded to 5 * 32
#define HID  512
#define OUT_ 128

typedef __attribute__((ext_vector_type(8))) short short8;
typedef __attribute__((ext_vector_type(4))) float f32x4;

__device__ __forceinline__ ushort f2b(float v) {
  __hip_bfloat16 h = __float2bfloat16(v);
  return *reinterpret_cast<ushort*>(&h);
}
__device__ __forceinline__ float4 add4(float4 a, float4 b) {
  return make_float4(a.x + b.x, a.y + b.y, a.z + b.z, a.w + b.w);
}

// ---------------------------------------------------------------------------
// Kernel A: blocks 0..39 convert W1 -> bf16 fragment order; block 40 zeroes
// out; blocks 41.. sparse aggregation + h_in fragment-order build.
// ---------------------------------------------------------------------------
__global__ __launch_bounds__(256) void k_prep_agg(
    const float* __restrict__ atom, const float* __restrict__ bond,
    const float* __restrict__ adj, const float* __restrict__ W1,
    ushort* __restrict__ w1f, ushort* __restrict__ hinf,
    float* __restrict__ out) {
  const int t = threadIdx.x;

  if (blockIdx.x < 40) {                       // ---- W1 conversion role ----
    const int U  = blockIdx.x * 256 + t;
    const int c  = U & 15;
    const int g  = (U >> 4) & 3;
    const int t5 = U >> 6;
    const int ks = t5 % 5;
    const int ntg = t5 / 5;
    const int n  = ntg * 16 + c;
    const int k0 = ks * 32 + g * 8;
    short8 v;
#pragma unroll
    for (int e = 0; e < 8; ++e) {
      const int k = k0 + e;
      v[e] = (short)f2b((k < K1) ? W1[k * HID + n] : 0.f);
    }
    reinterpret_cast<short8*>(w1f)[U] = v;
    return;
  }
  if (blockIdx.x == 40) {                      // ---- zero out[] role ----
    float4* o4 = reinterpret_cast<float4*>(out);
    for (int u = t; u < B_ * OUT_ / 4; u += 256)
      o4[u] = make_float4(0.f, 0.f, 0.f, 0.f);
    return;
  }

  // ---- aggregation role ----
  const int bid = blockIdx.x - 41;
  const int b  = bid >> 3;
  const int m  = bid & 7;
  const int j0 = m * 16;
  const int jl = t >> 4;   // 0..15 local row

  __shared__ float  sAdj[N_][16];    // 8 KB
  __shared__ ushort sList[16][N_];   // 4 KB compact active-i lists (sorted)
  __shared__ int    sCnt[16];
  __shared__ float4 sPart[16][4][4]; // 4 KB is-partials
  __shared__ ushort sRow[16][KP];    // 5 KB

  // stage adj column-slab [128 i][16 j], float4-vectorized
  const float* adjb = adj + (size_t)b * N_ * N_ + j0;
  for (int u = t; u < N_ * 4; u += 256) {
    const int i = u >> 2, q = u & 3;
    *reinterpret_cast<float4*>(&sAdj[i][q * 4]) =
        *reinterpret_cast<const float4*>(&adjb[(size_t)i * N_ + q * 4]);
  }
  __syncthreads();

  // ballot-compact: wave w handles j = w*4 .. w*4+3
  const int wv = t >> 6, l = t & 63;
#pragma unroll
  for (int q = 0; q < 4; ++q) {
    const int jj = wv * 4 + q;
    const float a0 = sAdj[l][jj];
    const float a1 = sAdj[l + 64][jj];
    const unsigned long long m0 = __ballot(a0 != 0.f);
    const unsigned long long m1 = __ballot(a1 != 0.f);
    const int c0 = __popcll(m0);
    unsigned int p0 = __builtin_amdgcn_mbcnt_lo((unsigned)m0, 0u);
    p0 = __builtin_amdgcn_mbcnt_hi((unsigned)(m0 >> 32), p0);
    if (a0 != 0.f) sList[jj][p0] = (ushort)l;
    unsigned int p1 = __builtin_amdgcn_mbcnt_lo((unsigned)m1, 0u);
    p1 = __builtin_amdgcn_mbcnt_hi((unsigned)(m1 >> 32), p1);
    if (a1 != 0.f) sList[jj][c0 + p1] = (ushort)(l + 64);
    if (l == 0) sCnt[jj] = c0 + __popcll(m1);
  }
  __syncthreads();

  // high-MLP gather: thread (jl, fq, is); is-threads stride 4 through the
  // sorted list with float4 loads (64B per (i,j) row covered by 4 fq lanes).
  {
    const int fq = (t >> 2) & 3;
    const int is = t & 3;
    const int cnt = sCnt[jl];
    const float4* bp4 = reinterpret_cast<const float4*>(
        bond + ((size_t)b * N_ * N_ + (j0 + jl)) * FB) + fq;
    // i stride in float4 units: N_*FB/4 = 512
    float4 a0 = {0,0,0,0}, a1 = {0,0,0,0}, a2 = {0,0,0,0}, a3 = {0,0,0,0};
    int e = is;
    for (; e + 12 < cnt; e += 16) {
      const int i0 = sList[jl][e];
      const int i1 = sList[jl][e + 4];
      const int i2 = sList[jl][e + 8];
      const int i3 = sList[jl][e + 12];
      a0 = add4(a0, bp4[(size_t)i0 * 512]);
      a1 = add4(a1, bp4[(size_t)i1 * 512]);
      a2 = add4(a2, bp4[(size_t)i2 * 512]);
      a3 = add4(a3, bp4[(size_t)i3 * 512]);
    }
    for (; e < cnt; e += 4) a0 = add4(a0, bp4[(size_t)sList[jl][e] * 512]);
    sPart[jl][fq][is] = add4(add4(a0, a1), add4(a2, a3));
  }
  __syncthreads();

  // combine is-partials + build bf16 row [atom | atom*deg | agg | 0-pad]
  {
    const int f = t & 15;
    const float* pc = reinterpret_cast<const float*>(&sPart[jl][f >> 2][0]);
    const float aggv = ((pc[f & 3] + pc[4 + (f & 3)]) +
                        (pc[8 + (f & 3)] + pc[12 + (f & 3)]));
    const float deg = (float)sCnt[jl];
    const float* ab = atom + ((size_t)b * N_ + j0 + jl) * FA;
    for (int c = f; c < FA; c += 16) {
      const float av = ab[c];
      sRow[jl][c]      = f2b(av);
      sRow[jl][FA + c] = f2b(av * deg);
    }
    sRow[jl][2 * FA + f] = f2b(aggv);
    sRow[jl][K1 + f]     = 0;
  }
  __syncthreads();

  uint4* dst = reinterpret_cast<uint4*>(hinf) + (size_t)(b * 8 + m) * 320;
  for (int u = t; u < 320; u += 256) {
    const int s = u >> 4, j2 = u & 15;        // s = ks*4 + g
    const int ks = s >> 2, g = s & 3;
    dst[ks * 64 + g * 16 + j2] =
        *reinterpret_cast<const uint4*>(&sRow[j2][s * 8]);
  }
}

// ---------------------------------------------------------------------------
// Fused GEMM1 + bias + relu + column-sum + (s @ W2) epilogue.
// block = (b, n-half). 512 thr = 8 waves; wave w owns 32 cols of the half.
// out must be zero on entry (kernel A block 40); exactly 2 commutative fp32
// atomicAdds per element -> deterministic.
// ---------------------------------------------------------------------------
__global__ __launch_bounds__(512) void k_gemm_out(
    const ushort* __restrict__ hinf, const ushort* __restrict__ w1f,
    const float* __restrict__ b1, const float* __restrict__ W2,
    const float* __restrict__ b2, float* __restrict__ out) {
  const int b  = blockIdx.x >> 1;
  const int nh = blockIdx.x & 1;
  const int t  = threadIdx.x;
  const int w  = t >> 6;
  const int l  = t & 63;

  __shared__ ushort sA[40 * 512];   // 40 KB fragment-ordered h_in[b]
  __shared__ float  sS[256];        // this half of s[b,:]
  __shared__ float  sRed[4][128];

  const uint4* g4 = reinterpret_cast<const uint4*>(hinf) + (size_t)b * 2560;
  uint4* s4 = reinterpret_cast<uint4*>(sA);
  for (int u = t; u < 2560; u += 512) s4[u] = g4[u];

  const int n0 = nh * 256 + w * 32;
  const short8* w8 = reinterpret_cast<const short8*>(w1f);
  short8 bfrag[2][5];
#pragma unroll
  for (int nt = 0; nt < 2; ++nt) {
    const int ntg = (n0 >> 4) + nt;
#pragma unroll
    for (int ks = 0; ks < 5; ++ks)
      bfrag[nt][ks] = w8[(ntg * 5 + ks) * 64 + l];
  }
  float bias[2];
#pragma unroll
  for (int nt = 0; nt < 2; ++nt) bias[nt] = b1[n0 + nt * 16 + (l & 15)];

  __syncthreads();

  const short8* a8 = reinterpret_cast<const short8*>(sA);
  float cs[2] = {0.f, 0.f};
  for (int m = 0; m < 8; ++m) {
    short8 af[5];
#pragma unroll
    for (int ks = 0; ks < 5; ++ks) af[ks] = a8[(m * 5 + ks) * 64 + l];
#pragma unroll
    for (int nt = 0; nt < 2; ++nt) {
      f32x4 acc = {0.f, 0.f, 0.f, 0.f};
#pragma unroll
      for (int ks = 0; ks < 5; ++ks)
        acc = __builtin_amdgcn_mfma_f32_16x16x32_bf16(af[ks], bfrag[nt][ks],
                                                      acc, 0, 0, 0);
      float p = 0.f;
#pragma unroll
      for (int r = 0; r < 4; ++r) p += fmaxf(acc[r] + bias[nt], 0.f);
      cs[nt] += p;
    }
  }

#pragma unroll
  for (int nt = 0; nt < 2; ++nt) {
    float v = cs[nt];
    v += __shfl_xor(v, 16);
    v += __shfl_xor(v, 32);
    if ((l >> 4) == 0) sS[w * 32 + nt * 16 + (l & 15)] = v;
  }
  __syncthreads();

  // epilogue: out[b,o] += sum_k sS[k] * W2[nh*256+k][o]  (+ N*b2 once)
  const int o = t & 127, kq = t >> 7;
  const float* W2p = W2 + (size_t)(nh * 256 + kq * 64) * OUT_ + o;
  float acc = 0.f;
#pragma unroll 8
  for (int k = 0; k < 64; ++k) acc += sS[kq * 64 + k] * W2p[(size_t)k * OUT_];
  sRed[kq][o] = acc;
  __syncthreads();
  if (kq == 0) {
    float v = (sRed[0][o] + sRed[1][o]) + (sRed[2][o] + sRed[3][o]);
    if (nh == 0) v += (float)N_ * b2[o];
    atomicAdd(&out[b * OUT_ + o], v);
  }
}

// ---------------------------------------------------------------------------
extern "C" void kernel_launch(void* const* d_in, const int* in_sizes, int n_in,
                              void* d_out, int out_size, void* d_ws, size_t ws_size,
                              hipStream_t stream) {
  const float* atom = (const float*)d_in[0];
  const float* bond = (const float*)d_in[1];
  const float* adj  = (const float*)d_in[2];
  const float* W1   = (const float*)d_in[3];
  const float* b1   = (const float*)d_in[4];
  const float* W2   = (const float*)d_in[5];
  const float* b2   = (const float*)d_in[6];
  float* out = (float*)d_out;

  ushort* hinf = (ushort*)d_ws;                       // 128*2560*16B = 5.24 MB
  ushort* w1f  = hinf + (size_t)B_ * 2560 * 8;        // 160 KB

  k_prep_agg<<<41 + B_ * 8, 256, 0, stream>>>(atom, bond, adj, W1, w1f, hinf,
                                              out);
  k_gemm_out<<<B_ * 2, 512, 0, stream>>>(hinf, w1f, b1, W2, b2, out);
}